// Round 5
// baseline (49.725 us; speedup 1.0000x reference)
//
#include <hip/hip_runtime.h>
#include <hip/hip_bf16.h>

#define HW 3136     // 56*56
#define CC 256
#define MM 72       // K*K*G (real)
#define HH 56
#define WW 56

typedef __attribute__((ext_vector_type(8))) short short8;   // 8 bf16 (4 VGPR)
typedef __attribute__((ext_vector_type(4))) float f32x4;    // MFMA acc / float4

#define WAITVM(n) asm volatile("s_waitcnt vmcnt(" #n ")" ::: "memory")

__device__ __forceinline__ void blockbar() {
    asm volatile("" ::: "memory");        // compiler fence: nothing crosses
    __builtin_amdgcn_s_barrier();         // raw barrier: NO auto vmcnt(0) drain
    asm volatile("" ::: "memory");
}

__device__ inline unsigned short f2b(float f) {
    unsigned u; __builtin_memcpy(&u, &f, 4);
    unsigned r = u + 0x7fffu + ((u >> 16) & 1u);   // RNE to bf16
    return (unsigned short)(r >> 16);
}
__device__ inline float b2f(unsigned short s) {
    unsigned u = ((unsigned)s) << 16; float f; __builtin_memcpy(&f, &u, 4);
    return f;
}
__device__ __forceinline__ unsigned short f2b_native(float f) {
    __hip_bfloat16 h = __float2bfloat16(f);
    unsigned short s; __builtin_memcpy(&s, &h, 2);
    return s;
}

// fire-and-forget 16B global -> LDS DMA (counted in vmcnt; LDS dst MUST be
// wave-uniform base + lane*16 -> all dst index maps below are linear in t)
__device__ __forceinline__ void gl2lds16(const float* g, float* l) {
    __builtin_amdgcn_global_load_lds(
        (const __attribute__((address_space(1))) void*)g,
        (__attribute__((address_space(3))) void*)l, 16, 0, 0);
}

// ---------------------------------------------------------------------------
// k0: fold the two 1x1 convs into bf16 W [80][256] (rows 72..95 zero) and
// fp32 bias [80]. (verified, unchanged)
// ---------------------------------------------------------------------------
__global__ __launch_bounds__(256) void k0_combine(
    const float* __restrict__ w_reduce,   // [128][256]
    const float* __restrict__ b_reduce,   // [128]
    const float* __restrict__ w_span,     // [72][128]
    const float* __restrict__ b_span,     // [72]
    unsigned short* __restrict__ wbf,     // [80][256] bf16
    float* __restrict__ bcomb)            // [80]
{
    __shared__ float red[4][64];
    __shared__ float redb[256];

    const int m  = blockIdx.x;       // 0..79
    const int cq = blockIdx.y;       // 0..3
    const int t  = threadIdx.x;
    const int oq = t >> 6;           // o-chunk (wave id)
    const int cl = t & 63;
    const int c  = cq * 64 + cl;

    float acc = 0.f;
    if (m < MM) {
        const float* wsB = w_span   + m * 128 + oq * 32;
        const float* wrB = w_reduce + (size_t)(oq * 32) * 256 + c;
#pragma unroll 8
        for (int o = 0; o < 32; ++o)
            acc = fmaf(wsB[o], wrB[(size_t)o * 256], acc);
    }
    if (oq != 0) red[oq][cl] = acc;
    __syncthreads();
    if (oq == 0)
        wbf[m * 256 + c] = f2b(acc + red[1][cl] + red[2][cl] + red[3][cl]);

    if (cq == 0) {   // uniform per block -> safe to sync inside
        redb[t] = (m < MM && t < 128) ? w_span[m * 128 + t] * b_reduce[t] : 0.f;
        __syncthreads();
#pragma unroll
        for (int s2 = 128; s2 > 0; s2 >>= 1) {
            if (t < s2) redb[t] += redb[t + s2];
            __syncthreads();
        }
        if (t == 0) bcomb[m] = (m < MM ? b_span[m] : 0.f) + redb[0];
    }
}

// ---------------------------------------------------------------------------
// k_fused: A section = depth-3 ring GEMM (round-4 VERIFIED form, tail vmcnt
// re-derived for removed B prefetches: p=6 -> 3/2, p=7 -> 0 one-time drain),
// ker parked in LDS bf16. B section = BARRIER-FREE streaming apply: taps
// from kl (read-only LDS), x via plain global loads (L3-resident re-read):
// per row, aligned f32x4 gives w1..w4; w0/w5 come from masked-clamped
// scalar loads (clamp keeps address in-bounds; the masked tap zeroes the
// value). No LDS staging, no vmcnt choreography, stores never gate loads.
// FP order of apply identical to verified rounds -> bit-identical output.
//
// Per-wave vmcnt ledger, A section only (stage = 3 VM ops waves 0-4 [t<320],
// 2 ops waves 5-6; prologue S0,S1,S2):
//   p=0..5 : vmcnt(6) / vmcnt(4)   (newer = 2 stages in flight)
//   p==6   : vmcnt(3) / vmcnt(2)   (newer = S7)
//   p==7   : vmcnt(0)              (one-time drain; B needs no ledger)
// grid(448 = 8*56 XCD swizzle), block(448). LDS 74496 B -> 2 blk/CU.
// ---------------------------------------------------------------------------
__global__ __launch_bounds__(448, 4) void k_fused(
    const float* __restrict__ x,              // [16][256][3136] fp32
    const unsigned short* __restrict__ wbf,   // [80][256] bf16
    const float* __restrict__ bcomb,          // [80]
    float* __restrict__ out)                  // [16][256][3136] fp32
{
    __shared__ __align__(16) float xsb[3 * 3584];           // 43008 B ring
    __shared__ __align__(16) unsigned short wsl[3][2560];   // 15360 B W ring
    __shared__ __align__(16) unsigned short kl[MM * 112];   // 16128 B ker bf16

    const int L   = blockIdx.x;               // 0..447
    const int wk  = (L & 7) * 56 + (L >> 3);  // bijective (448 = 8*56)
    const int b   = wk / 28;
    const int rem = wk - b * 28;
    const int ht  = rem >> 1;                 // 0..13
    const int cs  = rem & 1;                  // column half
    const int h0  = ht * 4;
    const int c0  = cs * 28;

    const int t    = threadIdx.x;             // 0..447
    const int lane = t & 63;
    const int wv   = t >> 6;                  // wave 0..6 = GEMM n-tile
    const int l15  = lane & 15;
    const int q    = lane >> 4;

    const int chh   = t / 28;                 // 0..15  (B: channel pair)
    const int rem28 = t - chh * 28;
    const int rA    = rem28 / 7;              // out row in band
    const int qA    = rem28 - rA * 7;         // 4-col strip

    const float* xb = x + (size_t)b * CC * HW;

    // ---- A-phase per-thread constants (identical to verified r2/r4) ----
    const int nb   = wv * 16 + l15;                // GEMM n = tile px
    const int nb2  = q * 112 + nb;                 // B-frag base (j stride 448)
    const int swA  = (l15 ^ (l15 >> 2)) & 3;       // A-frag XOR swizzle
    const int aBo  = l15 * 32 + (q ^ swA) * 8;     // A-frag base (mt stride 512)
    const int cA   = ((chh & 3) << 3) | (chh >> 2);// x-DMA channel perm
    const int pxo  = (h0 + rA) * WW + c0 + qA * 4; // x-DMA pixel offset
    const int wswr = ((t >> 2) ^ (t >> 4)) & 3;    // wbf pre-swizzled source
    const unsigned short* wsrc0 = wbf + (t >> 2) * 256 + ((t & 3) ^ wswr) * 8;

    // ---- apply masks (group-invariant) ----
    float vmm[3];
    int   hcB[3];
#pragma unroll
    for (int kh = 0; kh < 3; ++kh) {
        const int row = h0 + rA - 1 + kh;
        vmm[kh] = (row >= 0 && row < HH) ? 1.f : 0.f;
        hcB[kh] = row < 0 ? 0 : (row > 55 ? 55 : row);
    }
    const float lm  = (cs == 0 && qA == 0) ? 0.f : 1.f;   // w-1 < 0
    const float rmm = (cs == 1 && qA == 6) ? 0.f : 1.f;   // w+4 > 55
    const int colB = c0 + qA * 4;
    const int wl   = (lm  == 0.f) ? colB : colB - 1;      // clamped, masked
    const int wr   = (rmm == 0.f) ? 55   : colB + 4;      // clamped, masked

    // ---- stage helpers (LDS dst linear in t; slot = phase%3) ----
    auto stageX = [&](int s) {                // 2 DMA (rows chh, chh+16)
        const float* sp = xb + (size_t)(s * 32 + cA) * HW + pxo;
        float* dp = xsb + (s % 3) * 3584 + t * 4;
        gl2lds16(sp, dp);
        gl2lds16(sp + (size_t)4 * HW, dp + 1792);
    };
    auto stageW = [&](int s) {                // 1 DMA, waves 0-4 only
        if (t < 320)
            gl2lds16((const float*)(wsrc0 + s * 32), (float*)(wsl[s % 3]) + t * 4);
    };

    // ---- acc init (plain loads; older than all DMA -> drained by 1st wait)
    f32x4 acc[5];
#pragma unroll
    for (int mt = 0; mt < 5; ++mt)
#pragma unroll
        for (int r = 0; r < 4; ++r)
            acc[mt][r] = bcomb[mt * 16 + q * 4 + r];

    // ---- prologue: fill the ring ----
    stageX(0); stageW(0);
    stageX(1); stageW(1);
    stageX(2); stageW(2);

    // ---------------- A section: 8 pipelined GEMM phases ----------------
#pragma unroll 1
    for (int p = 0; p < 8; ++p) {
        if (p < 6)      { if (t < 320) WAITVM(6); else WAITVM(4); }
        else if (p == 6){ if (t < 320) WAITVM(3); else WAITVM(2); }
        else            { WAITVM(0); }
        blockbar();

        const float* bufA = xsb + (p % 3) * 3584;
        const unsigned short* wp = wsl[p % 3];
        union { short8 v; unsigned short u16[8]; } bq;
#pragma unroll
        for (int j = 0; j < 8; ++j)       // row j*4+q holds channel q*8+j
            bq.u16[j] = f2b_native(bufA[nb2 + j * 448]);
#pragma unroll
        for (int mt = 0; mt < 5; ++mt) {
            const short8 aq = *(const short8*)&wp[mt * 512 + aBo];
            acc[mt] = __builtin_amdgcn_mfma_f32_16x16x32_bf16(aq, bq.v, acc[mt], 0, 0, 0);
        }
        if (p == 7) {                     // ker -> LDS bf16 (rows 72..79 dropped)
#pragma unroll
            for (int mt = 0; mt < 5; ++mt)
#pragma unroll
                for (int r = 0; r < 4; ++r) {
                    const int m = mt * 16 + q * 4 + r;
                    if (m < MM) kl[m * 112 + nb] = f2b(acc[mt][r]);
                }
            asm volatile("s_waitcnt lgkmcnt(0)" ::: "memory");
        }
        blockbar();
        if (p <= 4) { stageX(p + 3); stageW(p + 3); }
    }

    // -------- B section: barrier-free streaming apply (8 x 32-ch groups) ----
#pragma unroll 1
    for (int gg = 0; gg < 8; ++gg) {
        ushort4 krb[9];
#pragma unroll
        for (int kk = 0; kk < 9; ++kk)
            krb[kk] = *(const ushort4*)&kl[(gg * 9 + kk) * 112 + rA * 28 + qA * 4];

        f32x4 kr[9];
#pragma unroll
        for (int kh = 0; kh < 3; ++kh) {
#pragma unroll
            for (int j = 0; j < 3; ++j) {
                const int kk = kh * 3 + j;
                kr[kk].x = b2f(krb[kk].x) * vmm[kh];
                kr[kk].y = b2f(krb[kk].y) * vmm[kh];
                kr[kk].z = b2f(krb[kk].z) * vmm[kh];
                kr[kk].w = b2f(krb[kk].w) * vmm[kh];
            }
            kr[kh * 3 + 0].x *= lm;       // tap reads col colB-1
            kr[kh * 3 + 2].w *= rmm;      // tap reads col colB+4
        }

        float* ob = out + ((size_t)b * CC + gg * 32 + chh * 2) * HW
                  + (h0 + rA) * WW + colB;
#pragma unroll
        for (int dd = 0; dd < 2; ++dd) {
            const float* base = xb + (size_t)(gg * 32 + chh * 2 + dd) * HW;
            f32x4 a = {0.f, 0.f, 0.f, 0.f};
#pragma unroll
            for (int kh = 0; kh < 3; ++kh) {
                const float* rowp = base + hcB[kh] * WW;
                const f32x4 q1v = *(const f32x4*)(rowp + colB);   // w1..w4
                const float w0 = rowp[wl];                        // col-1 (masked)
                const float w5 = rowp[wr];                        // col+4 (masked)
                const float w1 = q1v.x, w2 = q1v.y, w3 = q1v.z, w4 = q1v.w;
                const f32x4 k0v = kr[kh * 3 + 0];
                const f32x4 k1v = kr[kh * 3 + 1];
                const f32x4 k2v = kr[kh * 3 + 2];
                a.x = fmaf(k0v.x, w0, a.x); a.y = fmaf(k0v.y, w1, a.y);
                a.z = fmaf(k0v.z, w2, a.z); a.w = fmaf(k0v.w, w3, a.w);
                a.x = fmaf(k1v.x, w1, a.x); a.y = fmaf(k1v.y, w2, a.y);
                a.z = fmaf(k1v.z, w3, a.z); a.w = fmaf(k1v.w, w4, a.w);
                a.x = fmaf(k2v.x, w2, a.x); a.y = fmaf(k2v.y, w3, a.y);
                a.z = fmaf(k2v.z, w4, a.z); a.w = fmaf(k2v.w, w5, a.w);
            }
            *(f32x4*)(ob + (size_t)dd * HW) = a;
        }
    }
}

// ---------------------------------------------------------------------------
extern "C" void kernel_launch(void* const* d_in, const int* in_sizes, int n_in,
                              void* d_out, int out_size, void* d_ws, size_t ws_size,
                              hipStream_t stream) {
    const float* x        = (const float*)d_in[0];
    const float* w_reduce = (const float*)d_in[1];
    const float* b_reduce = (const float*)d_in[2];
    const float* w_span   = (const float*)d_in[3];
    const float* b_span   = (const float*)d_in[4];
    float* out = (float*)d_out;

    char* ws = (char*)d_ws;
    unsigned short* wbf   = (unsigned short*)ws;              // 40960 B
    float*          bcomb = (float*)(ws + 40960);             // 320 B

    k0_combine<<<dim3(80, 4), 256, 0, stream>>>(w_reduce, b_reduce, w_span, b_span,
                                                wbf, bcomb);
    k_fused<<<dim3(448), 448, 0, stream>>>(x, wbf, bcomb, out);
}

// Round 6
// 37.881 us; speedup vs baseline: 1.3127x; 1.3127x over previous
//
#include <hip/hip_runtime.h>
#include <hip/hip_bf16.h>

#define HW 3136     // 56*56
#define CC 256
#define MM 72       // K*K*G (real)
#define HH 56
#define WW 56

typedef __attribute__((ext_vector_type(8))) short short8;   // 8 bf16 (4 VGPR)
typedef __attribute__((ext_vector_type(4))) float f32x4;    // MFMA acc / float4

#define WAITVM(n) asm volatile("s_waitcnt vmcnt(" #n ")" ::: "memory")

__device__ __forceinline__ void blockbar() {
    asm volatile("" ::: "memory");        // compiler fence: nothing crosses
    __builtin_amdgcn_s_barrier();         // raw barrier: NO auto vmcnt(0) drain
    asm volatile("" ::: "memory");
}

__device__ inline unsigned short f2b(float f) {
    unsigned u; __builtin_memcpy(&u, &f, 4);
    unsigned r = u + 0x7fffu + ((u >> 16) & 1u);   // RNE to bf16
    return (unsigned short)(r >> 16);
}
__device__ inline float b2f(unsigned short s) {
    unsigned u = ((unsigned)s) << 16; float f; __builtin_memcpy(&f, &u, 4);
    return f;
}
__device__ __forceinline__ unsigned short f2b_native(float f) {
    __hip_bfloat16 h = __float2bfloat16(f);
    unsigned short s; __builtin_memcpy(&s, &h, 2);
    return s;
}

// fire-and-forget 16B global -> LDS DMA (counted in vmcnt; LDS dst MUST be
// wave-uniform base + lane*16 -> all dst index maps below are linear in t)
__device__ __forceinline__ void gl2lds16(const float* g, float* l) {
    __builtin_amdgcn_global_load_lds(
        (const __attribute__((address_space(1))) void*)g,
        (__attribute__((address_space(3))) void*)l, 16, 0, 0);
}

// ---------------------------------------------------------------------------
// k0: fold the two 1x1 convs into bf16 W [80][256] (rows 72..95 zero) and
// fp32 bias [80]. (verified, unchanged)
// ---------------------------------------------------------------------------
__global__ __launch_bounds__(256) void k0_combine(
    const float* __restrict__ w_reduce,   // [128][256]
    const float* __restrict__ b_reduce,   // [128]
    const float* __restrict__ w_span,     // [72][128]
    const float* __restrict__ b_span,     // [72]
    unsigned short* __restrict__ wbf,     // [80][256] bf16
    float* __restrict__ bcomb)            // [80]
{
    __shared__ float red[4][64];
    __shared__ float redb[256];

    const int m  = blockIdx.x;       // 0..79
    const int cq = blockIdx.y;       // 0..3
    const int t  = threadIdx.x;
    const int oq = t >> 6;           // o-chunk (wave id)
    const int cl = t & 63;
    const int c  = cq * 64 + cl;

    float acc = 0.f;
    if (m < MM) {
        const float* wsB = w_span   + m * 128 + oq * 32;
        const float* wrB = w_reduce + (size_t)(oq * 32) * 256 + c;
#pragma unroll 8
        for (int o = 0; o < 32; ++o)
            acc = fmaf(wsB[o], wrB[(size_t)o * 256], acc);
    }
    if (oq != 0) red[oq][cl] = acc;
    __syncthreads();
    if (oq == 0)
        wbf[m * 256 + c] = f2b(acc + red[1][cl] + red[2][cl] + red[3][cl]);

    if (cq == 0) {   // uniform per block -> safe to sync inside
        redb[t] = (m < MM && t < 128) ? w_span[m * 128 + t] * b_reduce[t] : 0.f;
        __syncthreads();
#pragma unroll
        for (int s2 = 128; s2 > 0; s2 >>= 1) {
            if (t < s2) redb[t] += redb[t + s2];
            __syncthreads();
        }
        if (t == 0) bcomb[m] = (m < MM ? b_span[m] : 0.f) + redb[0];
    }
}

// ---------------------------------------------------------------------------
// k_fused (single-barrier ring-3): 24 phases = 8 GEMM stages (32 ch) +
// 16 apply chunks (16 ch). ONE barrier per phase:
//    { WAITVM(N); barrier; stage(p+2); compute(p); }
// The top-of-phase barrier certifies all waves finished compute(p-1), which
// was the last reader of slot (p-1)%3 == (p+2)%3, so stage(p+2) may write it
// immediately -> earliest possible issue (~2 phases in flight), 24 barriers
// total (r4 had 48). All compute/layout/DMA maps identical to r4-verified.
//
// Per-wave vmcnt ledger (A stage = 3 VM ops t<320 / 2 else; B stage = 2;
// B compute ends with 1 store; in-order retirement, audited per phase):
//   prologue: stage(0), stage(1)
//   A p=0..6 : N = ops(stage(p+1)) = 3 / 2
//   A p==7   : N = ops(stage(8)=B0) = 2
//   B g2==0  : N = ops(B1) = 2
//   B g2=1..14: N = ops(B(g2+2)) + store(g2-1) = 3
//   B g2==15 : N = store(g2-1) = 1
// grid(448 = 8*56 XCD swizzle), block(448). LDS 74496 B -> 2 blk/CU.
// ---------------------------------------------------------------------------
__global__ __launch_bounds__(448, 4) void k_fused(
    const float* __restrict__ x,              // [16][256][3136] fp32
    const unsigned short* __restrict__ wbf,   // [80][256] bf16
    const float* __restrict__ bcomb,          // [80]
    float* __restrict__ out)                  // [16][256][3136] fp32
{
    __shared__ __align__(16) float xsb[3 * 3584];           // 43008 B ring
    __shared__ __align__(16) unsigned short wsl[3][2560];   // 15360 B W ring
    __shared__ __align__(16) unsigned short kl[MM * 112];   // 16128 B ker bf16

    const int L   = blockIdx.x;               // 0..447
    const int wk  = (L & 7) * 56 + (L >> 3);  // bijective (448 = 8*56)
    const int b   = wk / 28;
    const int rem = wk - b * 28;
    const int ht  = rem >> 1;                 // 0..13
    const int cs  = rem & 1;                  // column half
    const int h0  = ht * 4;
    const int c0  = cs * 28;

    const int t    = threadIdx.x;             // 0..447
    const int lane = t & 63;
    const int wv   = t >> 6;                  // wave 0..6 = GEMM n-tile
    const int l15  = lane & 15;
    const int q    = lane >> 4;

    const int chh   = t / 28;                 // 0..15  (B: channel in chunk)
    const int rem28 = t - chh * 28;
    const int rA    = rem28 / 7;              // out row in band
    const int qA    = rem28 - rA * 7;         // 4-col strip

    const float* xb = x + (size_t)b * CC * HW;

    // ---- A-phase per-thread constants (identical to verified r2/r4) ----
    const int nb   = wv * 16 + l15;                // GEMM n = tile px
    const int nb2  = q * 112 + nb;                 // B-frag base (j stride 448)
    const int swA  = (l15 ^ (l15 >> 2)) & 3;       // A-frag XOR swizzle
    const int aBo  = l15 * 32 + (q ^ swA) * 8;     // A-frag base (mt stride 512)
    const int cA   = ((chh & 3) << 3) | (chh >> 2);// x-DMA channel perm
    const int pxo  = (h0 + rA) * WW + c0 + qA * 4; // x-DMA pixel offset
    const int wswr = ((t >> 2) ^ (t >> 4)) & 3;    // wbf pre-swizzled source
    const unsigned short* wsrc0 = wbf + (t >> 2) * 256 + ((t & 3) ^ wswr) * 8;

    // ---- B-phase staging source offsets (chunk-invariant) ----
    int boff[2];
#pragma unroll
    for (int i = 0; i < 2; ++i) {
        const int f  = i * 448 + t;
        const int fc = f < 864 ? f : 863;     // tail lanes: clamped-dup source
        const int d  = fc / 54;               // ch in chunk 0..15
        const int r2 = fc - d * 54;
        const int rr = r2 / 9;                // stage row 0..5 (h0-1..h0+4)
        const int qd = r2 - rr * 9;           // quad 0..8
        const int hh = h0 - 1 + rr;
        const int hc = hh < 0 ? 0 : (hh > 55 ? 55 : hh);
        int colc = c0 - 4 + qd * 4;           // 16B-aligned; borders masked
        colc = colc < 0 ? 0 : (colc > 52 ? 52 : colc);
        boff[i] = d * HW + hc * WW + colc;
    }

    // ---- apply masks (chunk-invariant) ----
    float vmm[3];
#pragma unroll
    for (int kh = 0; kh < 3; ++kh) {
        const int row = h0 + rA - 1 + kh;
        vmm[kh] = (row >= 0 && row < HH) ? 1.f : 0.f;
    }
    const float lm  = (cs == 0 && qA == 0) ? 0.f : 1.f;   // w-1 < 0
    const float rmm = (cs == 1 && qA == 6) ? 0.f : 1.f;   // w+4 > 55

    // ---- stage helpers (LDS dst linear in t; slot = phase%3) ----
    auto stageX = [&](int s) {                // 2 DMA (rows chh, chh+16)
        const float* sp = xb + (size_t)(s * 32 + cA) * HW + pxo;
        float* dp = xsb + (s % 3) * 3584 + t * 4;
        gl2lds16(sp, dp);
        gl2lds16(sp + (size_t)4 * HW, dp + 1792);
    };
    auto stageW = [&](int s) {                // 1 DMA, waves 0-4 only
        if (t < 320)
            gl2lds16((const float*)(wsrc0 + s * 32), (float*)(wsl[s % 3]) + t * 4);
    };
    auto stageB = [&](int c) {                // 2 DMA (16-ch halo chunk)
        const float* gp = xb + (size_t)(c * 16) * HW;
        float* dp = xsb + ((8 + c) % 3) * 3584;   // phase (8+c) -> slot
        gl2lds16(gp + boff[0], dp + t * 4);
        gl2lds16(gp + boff[1], dp + (448 + t) * 4);
    };

    // ---- acc init (plain loads; older than all DMA -> drained by 1st wait)
    f32x4 acc[5];
#pragma unroll
    for (int mt = 0; mt < 5; ++mt)
#pragma unroll
        for (int r = 0; r < 4; ++r)
            acc[mt][r] = bcomb[mt * 16 + q * 4 + r];

    // ---- prologue: 2 stages in flight ----
    stageX(0); stageW(0);
    stageX(1); stageW(1);

    // ---------------- A section: 8 GEMM phases, 1 barrier each ----------------
#pragma unroll 1
    for (int p = 0; p < 8; ++p) {
        if (p < 7) { if (t < 320) WAITVM(3); else WAITVM(2); }
        else       { WAITVM(2); }
        blockbar();
        // stage(p+2) into the slot freed by compute(p-1)
        if (p < 6)       { stageX(p + 2); stageW(p + 2); }
        else if (p == 6) { stageB(0); }    // phase 8
        else             { stageB(1); }    // phase 9

        const float* bufA = xsb + (p % 3) * 3584;
        const unsigned short* wp = wsl[p % 3];
        union { short8 v; unsigned short u16[8]; } bq;
#pragma unroll
        for (int j = 0; j < 8; ++j)       // row j*4+q holds channel q*8+j
            bq.u16[j] = f2b_native(bufA[nb2 + j * 448]);
#pragma unroll
        for (int mt = 0; mt < 5; ++mt) {
            const short8 aq = *(const short8*)&wp[mt * 512 + aBo];
            acc[mt] = __builtin_amdgcn_mfma_f32_16x16x32_bf16(aq, bq.v, acc[mt], 0, 0, 0);
        }
        if (p == 7) {                     // ker -> LDS bf16 (rows 72..79 dropped)
#pragma unroll
            for (int mt = 0; mt < 5; ++mt)
#pragma unroll
                for (int r = 0; r < 4; ++r) {
                    const int m = mt * 16 + q * 4 + r;
                    if (m < MM) kl[m * 112 + nb] = f2b(acc[mt][r]);
                }
            asm volatile("s_waitcnt lgkmcnt(0)" ::: "memory");
        }
    }

    // ---------------- B section: 16 apply phases, 1 barrier each --------------
    f32x4 kr[9];
#pragma unroll 1
    for (int g2 = 0; g2 < 16; ++g2) {
        if (g2 == 0)       WAITVM(2);
        else if (g2 <= 14) WAITVM(3);
        else               WAITVM(1);
        blockbar();
        if (g2 <= 13) stageB(g2 + 2);     // into slot freed by compute(g2-1)

        if ((g2 & 1) == 0) {              // taps shared by both chunk halves
            const int g = g2 >> 1;
            ushort4 krb[9];
#pragma unroll
            for (int kk = 0; kk < 9; ++kk)
                krb[kk] = *(const ushort4*)&kl[(g * 9 + kk) * 112 + rA * 28 + qA * 4];
#pragma unroll
            for (int kh = 0; kh < 3; ++kh) {
#pragma unroll
                for (int j = 0; j < 3; ++j) {
                    const int kk = kh * 3 + j;
                    kr[kk].x = b2f(krb[kk].x) * vmm[kh];
                    kr[kk].y = b2f(krb[kk].y) * vmm[kh];
                    kr[kk].z = b2f(krb[kk].z) * vmm[kh];
                    kr[kk].w = b2f(krb[kk].w) * vmm[kh];
                }
                kr[kh * 3 + 0].x *= lm;   // tap reads col c0+4qA-1
                kr[kh * 3 + 2].w *= rmm;  // tap reads col c0+4qA+4
            }
        }

        const float* bp = xsb + ((8 + g2) % 3) * 3584 + chh * 216;
        f32x4 a = {0.f, 0.f, 0.f, 0.f};
#pragma unroll
        for (int kh = 0; kh < 3; ++kh) {
            const float* rowp = bp + (rA + kh) * 36;
            const f32x4 q0v = *(const f32x4*)(rowp + qA * 4);      // .w = w0-1
            const f32x4 q1v = *(const f32x4*)(rowp + qA * 4 + 4);  // w0..w0+3
            const float tl  = rowp[qA * 4 + 8];                    // w0+4
            const float w0 = q0v.w, w1 = q1v.x, w2 = q1v.y,
                        w3 = q1v.z, w4 = q1v.w, w5 = tl;
            const f32x4 k0v = kr[kh * 3 + 0];
            const f32x4 k1v = kr[kh * 3 + 1];
            const f32x4 k2v = kr[kh * 3 + 2];
            a.x = fmaf(k0v.x, w0, a.x); a.y = fmaf(k0v.y, w1, a.y);
            a.z = fmaf(k0v.z, w2, a.z); a.w = fmaf(k0v.w, w3, a.w);
            a.x = fmaf(k1v.x, w1, a.x); a.y = fmaf(k1v.y, w2, a.y);
            a.z = fmaf(k1v.z, w3, a.z); a.w = fmaf(k1v.w, w4, a.w);
            a.x = fmaf(k2v.x, w2, a.x); a.y = fmaf(k2v.y, w3, a.y);
            a.z = fmaf(k2v.z, w4, a.z); a.w = fmaf(k2v.w, w5, a.w);
        }
        float* ob = out + ((size_t)b * CC + g2 * 16 + chh) * HW
                  + (h0 + rA) * WW + c0 + qA * 4;
        *(f32x4*)ob = a;                  // 1 store per thread per phase
    }
}

// ---------------------------------------------------------------------------
extern "C" void kernel_launch(void* const* d_in, const int* in_sizes, int n_in,
                              void* d_out, int out_size, void* d_ws, size_t ws_size,
                              hipStream_t stream) {
    const float* x        = (const float*)d_in[0];
    const float* w_reduce = (const float*)d_in[1];
    const float* b_reduce = (const float*)d_in[2];
    const float* w_span   = (const float*)d_in[3];
    const float* b_span   = (const float*)d_in[4];
    float* out = (float*)d_out;

    char* ws = (char*)d_ws;
    unsigned short* wbf   = (unsigned short*)ws;              // 40960 B
    float*          bcomb = (float*)(ws + 40960);             // 320 B

    k0_combine<<<dim3(80, 4), 256, 0, stream>>>(w_reduce, b_reduce, w_span, b_span,
                                                wbf, bcomb);
    k_fused<<<dim3(448), 448, 0, stream>>>(x, wbf, bcomb, out);
}